// Round 1
// 1696.441 us; speedup vs baseline: 1.1446x; 1.1446x over previous
//
#include <hip/hip_runtime.h>
#include <hip/hip_bf16.h>
#include <math.h>

// Problem constants (from reference)
#define B_   4
#define S_   4000
#define DIN  1024
#define DA   512
#define L_   8921

typedef __attribute__((ext_vector_type(8))) short          short8;  // 8 bf16 = 4 VGPRs (MFMA A/B frag)
typedef __attribute__((ext_vector_type(4))) float          f4;      // 4 f32 (MFMA C/D frag)
typedef __attribute__((ext_vector_type(4))) unsigned int   u4;      // 16B vector for LDS/global moves
typedef __attribute__((ext_vector_type(4))) unsigned short us4;     // 8B vector (4 bf16)

// f32 -> bf16 round-to-nearest-even (finite inputs only; fine here)
static __device__ __forceinline__ unsigned short f2b(float f) {
    unsigned int u = __float_as_uint(f);
    u += 0x7fffu + ((u >> 16) & 1u);
    return (unsigned short)(u >> 16);
}
static __device__ __forceinline__ unsigned int pack2(float lo, float hi) {
    return (unsigned int)f2b(lo) | ((unsigned int)f2b(hi) << 16);
}
static __device__ __forceinline__ float b2f(unsigned short u) {
    return __uint_as_float(((unsigned int)u) << 16);
}

// ---------------------------------------------------------------------------
// Kernel 1: z = tanh(x @ W^T + b)   [16000 x 512], output bf16 into ws
// 128x128 tile, BK=32, 4 waves in 2x2, each wave 64x64 (4x4 frags of 16x16x32)
// ---------------------------------------------------------------------------
__global__ __launch_bounds__(256) void k_z(const float* __restrict__ x,
                                           const float* __restrict__ Ww,
                                           const float* __restrict__ Wb,
                                           unsigned short* __restrict__ z)
{
    __shared__ unsigned short lds_a[128 * 32];
    __shared__ unsigned short lds_b[128 * 32];

    const int tid  = threadIdx.x;
    const int lane = tid & 63;
    const int w    = tid >> 6;
    const int wm   = w >> 1, wn = w & 1;
    const int q    = lane >> 4, r = lane & 15;
    const int m0   = blockIdx.x * 128;
    const int n0   = blockIdx.y * 128;

    f4 acc[4][4];
#pragma unroll
    for (int i = 0; i < 4; i++)
#pragma unroll
        for (int j = 0; j < 4; j++) { f4 zz = {0.f,0.f,0.f,0.f}; acc[i][j] = zz; }

    const int row  = tid >> 1;     // 0..127
    const int half = tid & 1;      // 16 f32 each

    for (int kk = 0; kk < DIN; kk += 32) {
        // A tile: x rows (M exact multiple of 128, no guard)
        {
            const f4* src = (const f4*)(x + (size_t)(m0 + row) * DIN + kk + half * 16);
            f4 v0 = src[0], v1 = src[1], v2 = src[2], v3 = src[3];
            u4* dst = (u4*)&lds_a[row * 32 + half * 16];
            u4 o0, o1;
            o0[0] = pack2(v0[0], v0[1]); o0[1] = pack2(v0[2], v0[3]);
            o0[2] = pack2(v1[0], v1[1]); o0[3] = pack2(v1[2], v1[3]);
            o1[0] = pack2(v2[0], v2[1]); o1[1] = pack2(v2[2], v2[3]);
            o1[2] = pack2(v3[0], v3[1]); o1[3] = pack2(v3[2], v3[3]);
            dst[0] = o0; dst[1] = o1;
        }
        // B tile: W rows (N = 512 exact, no guard)
        {
            const f4* src = (const f4*)(Ww + (size_t)(n0 + row) * DIN + kk + half * 16);
            f4 v0 = src[0], v1 = src[1], v2 = src[2], v3 = src[3];
            u4* dst = (u4*)&lds_b[row * 32 + half * 16];
            u4 o0, o1;
            o0[0] = pack2(v0[0], v0[1]); o0[1] = pack2(v0[2], v0[3]);
            o0[2] = pack2(v1[0], v1[1]); o0[3] = pack2(v1[2], v1[3]);
            o1[0] = pack2(v2[0], v2[1]); o1[1] = pack2(v2[2], v2[3]);
            o1[2] = pack2(v3[0], v3[1]); o1[3] = pack2(v3[2], v3[3]);
            dst[0] = o0; dst[1] = o1;
        }
        __syncthreads();

        short8 af[4], bfr[4];
#pragma unroll
        for (int i = 0; i < 4; i++) {
            af[i]  = *(const short8*)&lds_a[(wm * 64 + i * 16 + r) * 32 + q * 8];
            bfr[i] = *(const short8*)&lds_b[(wn * 64 + i * 16 + r) * 32 + q * 8];
        }
#pragma unroll
        for (int i = 0; i < 4; i++)
#pragma unroll
            for (int j = 0; j < 4; j++)
                acc[i][j] = __builtin_amdgcn_mfma_f32_16x16x32_bf16(af[i], bfr[j], acc[i][j], 0, 0, 0);
        __syncthreads();
    }

    // epilogue: tanh(acc + bias) -> bf16 z
#pragma unroll
    for (int i = 0; i < 4; i++) {
#pragma unroll
        for (int j = 0; j < 4; j++) {
            const int col = n0 + wn * 64 + j * 16 + r;
            const float bias = Wb[col];
#pragma unroll
            for (int e = 0; e < 4; e++) {
                const int rowg = m0 + wm * 64 + i * 16 + q * 4 + e;
                z[(size_t)rowg * DA + col] = f2b(tanhf(acc[i][j][e] + bias));
            }
        }
    }
}

// ---------------------------------------------------------------------------
// Kernel cvt: elementwise f32 -> bf16 (for U_w, V_w). n8 = #elements/8.
// ---------------------------------------------------------------------------
__global__ __launch_bounds__(256) void k_cvt(const float* __restrict__ src,
                                             unsigned short* __restrict__ dst, int n8)
{
    const int i = blockIdx.x * 256 + threadIdx.x;
    if (i < n8) {
        const f4* s = (const f4*)src + (size_t)i * 2;
        const f4 a = s[0], b = s[1];
        u4 o;
        o[0] = pack2(a[0], a[1]); o[1] = pack2(a[2], a[3]);
        o[2] = pack2(b[0], b[1]); o[3] = pack2(b[2], b[3]);
        *((u4*)dst + i) = o;
    }
}

// ---------------------------------------------------------------------------
// Kernel uv (NEW): dual GEMM sharing the z staging.
//   scores[b,l,s] = U[l,:] . z[b,s,:]   -> f32 (alpha region of d_out)
//   T[b,l,s]      = V[l,:] . z[b,s,:]   -> f32 or bf16 (ws)
// M=L (8921), N=S (4000), K=DA (512). 128x128 tile, BK=32,
// each wave: 2 x (4x4) accumulators (64x64 for U-GEMM and V-GEMM).
// ---------------------------------------------------------------------------
template<bool TB16>
__global__ __launch_bounds__(256) void k_uv(const unsigned short* __restrict__ Ubf,
                                            const unsigned short* __restrict__ Vbf,
                                            const unsigned short* __restrict__ z,
                                            float* __restrict__ scores,
                                            void* __restrict__ Tout)
{
    __shared__ unsigned short lds_u[128 * 32];
    __shared__ unsigned short lds_v[128 * 32];
    __shared__ unsigned short lds_z[128 * 32];

    const int tid  = threadIdx.x;
    const int lane = tid & 63;
    const int w    = tid >> 6;
    const int wm   = w >> 1, wn = w & 1;
    const int q    = lane >> 4, r = lane & 15;
    const int b    = blockIdx.z;
    const int m0   = blockIdx.x * 128;   // label block
    const int n0   = blockIdx.y * 128;   // sequence block

    f4 accU[4][4], accV[4][4];
#pragma unroll
    for (int i = 0; i < 4; i++)
#pragma unroll
        for (int j = 0; j < 4; j++) {
            f4 zz = {0.f,0.f,0.f,0.f};
            accU[i][j] = zz; accV[i][j] = zz;
        }

    const int srow = tid >> 2;  // 0..63
    const int sseg = tid & 3;   // 16B segments

    for (int kk = 0; kk < DA; kk += 32) {
#pragma unroll
        for (int jj = 0; jj < 2; jj++) {
            const int rr = srow + jj * 64;
            const int gm = m0 + rr;
            const int gs = n0 + rr;
            u4 zz = {0,0,0,0};
            u4 vu = zz, vv = zz, vz = zz;
            if (gm < L_) {
                vu = *(const u4*)&Ubf[(size_t)gm * DA + kk + sseg * 8];
                vv = *(const u4*)&Vbf[(size_t)gm * DA + kk + sseg * 8];
            }
            if (gs < S_) {
                vz = *(const u4*)&z[((size_t)(b * S_ + gs)) * DA + kk + sseg * 8];
            }
            *(u4*)&lds_u[rr * 32 + sseg * 8] = vu;
            *(u4*)&lds_v[rr * 32 + sseg * 8] = vv;
            *(u4*)&lds_z[rr * 32 + sseg * 8] = vz;
        }
        __syncthreads();

        short8 fu[4], fv[4], fz[4];
#pragma unroll
        for (int i = 0; i < 4; i++) {
            fu[i] = *(const short8*)&lds_u[(wm * 64 + i * 16 + r) * 32 + q * 8];
            fv[i] = *(const short8*)&lds_v[(wm * 64 + i * 16 + r) * 32 + q * 8];
            fz[i] = *(const short8*)&lds_z[(wn * 64 + i * 16 + r) * 32 + q * 8];
        }
#pragma unroll
        for (int i = 0; i < 4; i++)
#pragma unroll
            for (int j = 0; j < 4; j++) {
                accU[i][j] = __builtin_amdgcn_mfma_f32_16x16x32_bf16(fu[i], fz[j], accU[i][j], 0, 0, 0);
                accV[i][j] = __builtin_amdgcn_mfma_f32_16x16x32_bf16(fv[i], fz[j], accV[i][j], 0, 0, 0);
            }
        __syncthreads();
    }

#pragma unroll
    for (int i = 0; i < 4; i++) {
#pragma unroll
        for (int j = 0; j < 4; j++) {
            const int colg = n0 + wn * 64 + j * 16 + r;
#pragma unroll
            for (int e = 0; e < 4; e++) {
                const int rowg = m0 + wm * 64 + i * 16 + q * 4 + e;
                if (rowg < L_ && colg < S_) {
                    const size_t idx = ((size_t)b * L_ + rowg) * S_ + colg;
                    scores[idx] = accU[i][j][e];
                    if constexpr (TB16) ((unsigned short*)Tout)[idx] = f2b(accV[i][j][e]);
                    else                ((float*)Tout)[idx]          = accV[i][j][e];
                }
            }
        }
    }
}

// ---------------------------------------------------------------------------
// Kernel fsy (NEW): per (b,l) row — softmax(scores) in-place -> alpha,
// fused with y[b,l] = sum_s alpha*T + Vb[l]. Pure streaming, 1 block/row.
// ---------------------------------------------------------------------------
template<bool TB16>
__global__ __launch_bounds__(256) void k_fsy(float* __restrict__ sc,
                                             const void* __restrict__ Tin,
                                             const float* __restrict__ Vbias,
                                             float* __restrict__ y)
{
    const size_t rb = (size_t)blockIdx.x * S_;
    float* p = sc + rb;
    const int tid = threadIdx.x;

    f4 v[4];
    float mx = -3.4e38f;
#pragma unroll
    for (int j = 0; j < 4; j++) {
        const int vi = tid + j * 256;
        if (vi < S_ / 4) {
            v[j] = ((const f4*)p)[vi];
            mx = fmaxf(mx, fmaxf(fmaxf(v[j][0], v[j][1]), fmaxf(v[j][2], v[j][3])));
        }
    }
#pragma unroll
    for (int off = 32; off > 0; off >>= 1) mx = fmaxf(mx, __shfl_xor(mx, off, 64));

    __shared__ float red[12];
    if ((tid & 63) == 0) red[tid >> 6] = mx;
    __syncthreads();
    mx = fmaxf(fmaxf(red[0], red[1]), fmaxf(red[2], red[3]));

    float s = 0.f;
#pragma unroll
    for (int j = 0; j < 4; j++) {
        const int vi = tid + j * 256;
        if (vi < S_ / 4) {
#pragma unroll
            for (int c = 0; c < 4; c++) { v[j][c] = __expf(v[j][c] - mx); s += v[j][c]; }
        }
    }
#pragma unroll
    for (int off = 32; off > 0; off >>= 1) s += __shfl_xor(s, off, 64);
    if ((tid & 63) == 0) red[4 + (tid >> 6)] = s;
    __syncthreads();
    s = red[4] + red[5] + red[6] + red[7];
    const float inv = 1.f / s;

    float yp = 0.f;
#pragma unroll
    for (int j = 0; j < 4; j++) {
        const int vi = tid + j * 256;
        if (vi < S_ / 4) {
            f4 o = v[j];
            o[0] *= inv; o[1] *= inv; o[2] *= inv; o[3] *= inv;
            ((f4*)p)[vi] = o;
            if constexpr (TB16) {
                const us4 tv = ((const us4*)((const unsigned short*)Tin + rb))[vi];
                yp += o[0] * b2f(tv[0]) + o[1] * b2f(tv[1]) + o[2] * b2f(tv[2]) + o[3] * b2f(tv[3]);
            } else {
                const f4 tv = ((const f4*)((const float*)Tin + rb))[vi];
                yp += o[0] * tv[0] + o[1] * tv[1] + o[2] * tv[2] + o[3] * tv[3];
            }
        }
    }
#pragma unroll
    for (int off = 32; off > 0; off >>= 1) yp += __shfl_xor(yp, off, 64);
    if ((tid & 63) == 0) red[8 + (tid >> 6)] = yp;
    __syncthreads();
    if (tid == 0) {
        const int l = (int)(blockIdx.x % (unsigned)L_);
        y[blockIdx.x] = red[8] + red[9] + red[10] + red[11] + Vbias[l];
    }
}

// ===========================================================================
// ===== Fallback path (previous verified kernels), used if ws too small =====
// ===========================================================================
__global__ __launch_bounds__(256) void k_scores(const float* __restrict__ U,
                                                const unsigned short* __restrict__ z,
                                                float* __restrict__ out)
{
    __shared__ unsigned short lds_a[128 * 32];
    __shared__ unsigned short lds_b[128 * 32];

    const int tid  = threadIdx.x;
    const int lane = tid & 63;
    const int w    = tid >> 6;
    const int wm   = w >> 1, wn = w & 1;
    const int q    = lane >> 4, r = lane & 15;
    const int b    = blockIdx.z;
    const int m0   = blockIdx.x * 128;
    const int n0   = blockIdx.y * 128;

    f4 acc[4][4];
#pragma unroll
    for (int i = 0; i < 4; i++)
#pragma unroll
        for (int j = 0; j < 4; j++) { f4 zz = {0.f,0.f,0.f,0.f}; acc[i][j] = zz; }

    const int row  = tid >> 1;
    const int half = tid & 1;
    const int brow = tid >> 2;
    const int bseg = tid & 3;

    for (int kk = 0; kk < DA; kk += 32) {
        {
            u4* dst = (u4*)&lds_a[row * 32 + half * 16];
            const int gm = m0 + row;
            if (gm < L_) {
                const f4* src = (const f4*)(U + (size_t)gm * DA + kk + half * 16);
                f4 v0 = src[0], v1 = src[1], v2 = src[2], v3 = src[3];
                u4 o0, o1;
                o0[0] = pack2(v0[0], v0[1]); o0[1] = pack2(v0[2], v0[3]);
                o0[2] = pack2(v1[0], v1[1]); o0[3] = pack2(v1[2], v1[3]);
                o1[0] = pack2(v2[0], v2[1]); o1[1] = pack2(v2[2], v2[3]);
                o1[2] = pack2(v3[0], v3[1]); o1[3] = pack2(v3[2], v3[3]);
                dst[0] = o0; dst[1] = o1;
            } else {
                u4 zz = {0,0,0,0}; dst[0] = zz; dst[1] = zz;
            }
        }
#pragma unroll
        for (int jj = 0; jj < 2; jj++) {
            const int rr = brow + jj * 64;
            const int gs = n0 + rr;
            u4* dst = (u4*)&lds_b[rr * 32 + bseg * 8];
            if (gs < S_) {
                *dst = *(const u4*)&z[((size_t)(b * S_ + gs)) * DA + kk + bseg * 8];
            } else {
                u4 zz = {0,0,0,0}; *dst = zz;
            }
        }
        __syncthreads();

        short8 af[4], bfr[4];
#pragma unroll
        for (int i = 0; i < 4; i++) {
            af[i]  = *(const short8*)&lds_a[(wm * 64 + i * 16 + r) * 32 + q * 8];
            bfr[i] = *(const short8*)&lds_b[(wn * 64 + i * 16 + r) * 32 + q * 8];
        }
#pragma unroll
        for (int i = 0; i < 4; i++)
#pragma unroll
            for (int j = 0; j < 4; j++)
                acc[i][j] = __builtin_amdgcn_mfma_f32_16x16x32_bf16(af[i], bfr[j], acc[i][j], 0, 0, 0);
        __syncthreads();
    }

#pragma unroll
    for (int i = 0; i < 4; i++) {
#pragma unroll
        for (int j = 0; j < 4; j++) {
            const int colg = n0 + wn * 64 + j * 16 + r;
#pragma unroll
            for (int e = 0; e < 4; e++) {
                const int rowg = m0 + wm * 64 + i * 16 + q * 4 + e;
                if (rowg < L_ && colg < S_)
                    out[((size_t)b * L_ + rowg) * S_ + colg] = acc[i][j][e];
            }
        }
    }
}

__global__ __launch_bounds__(256) void k_softmax(float* __restrict__ a)
{
    float* p = a + (size_t)blockIdx.x * S_;
    const int tid = threadIdx.x;

    f4 v[4];
    float mx = -3.4e38f;
#pragma unroll
    for (int j = 0; j < 4; j++) {
        const int vi = tid + j * 256;
        if (vi < S_ / 4) {
            v[j] = ((const f4*)p)[vi];
            mx = fmaxf(mx, fmaxf(fmaxf(v[j][0], v[j][1]), fmaxf(v[j][2], v[j][3])));
        }
    }
#pragma unroll
    for (int off = 32; off > 0; off >>= 1) mx = fmaxf(mx, __shfl_xor(mx, off, 64));

    __shared__ float red[8];
    if ((tid & 63) == 0) red[tid >> 6] = mx;
    __syncthreads();
    mx = fmaxf(fmaxf(red[0], red[1]), fmaxf(red[2], red[3]));

    float s = 0.f;
#pragma unroll
    for (int j = 0; j < 4; j++) {
        const int vi = tid + j * 256;
        if (vi < S_ / 4) {
#pragma unroll
            for (int c = 0; c < 4; c++) { v[j][c] = __expf(v[j][c] - mx); s += v[j][c]; }
        }
    }
#pragma unroll
    for (int off = 32; off > 0; off >>= 1) s += __shfl_xor(s, off, 64);
    if ((tid & 63) == 0) red[4 + (tid >> 6)] = s;
    __syncthreads();
    s = red[4] + red[5] + red[6] + red[7];

    const float inv = 1.f / s;
#pragma unroll
    for (int j = 0; j < 4; j++) {
        const int vi = tid + j * 256;
        if (vi < S_ / 4) {
            f4 o = v[j]; o[0] *= inv; o[1] *= inv; o[2] *= inv; o[3] *= inv;
            ((f4*)p)[vi] = o;
        }
    }
}

__global__ __launch_bounds__(256) void k_transpose(const unsigned short* __restrict__ z,
                                                   unsigned short* __restrict__ zT)
{
    __shared__ unsigned short t[32][33];
    const int b  = blockIdx.z;
    const int s0 = blockIdx.x * 32;
    const int a0 = blockIdx.y * 32;
    const int c  = threadIdx.x & 31;
    const int r4 = threadIdx.x >> 5;

#pragma unroll
    for (int i = 0; i < 4; i++) {
        const int sl = r4 * 4 + i;
        t[sl][c] = z[((size_t)(b * S_ + s0 + sl)) * DA + a0 + c];
    }
    __syncthreads();
#pragma unroll
    for (int i = 0; i < 4; i++) {
        const int al = r4 * 4 + i;
        zT[((size_t)(b * DA + a0 + al)) * S_ + s0 + c] = t[c][al];
    }
}

__global__ __launch_bounds__(256) void k_mv(const float* __restrict__ alpha,
                                            const unsigned short* __restrict__ zT,
                                            const float* __restrict__ Vw,
                                            const float* __restrict__ Vb,
                                            float* __restrict__ y)
{
    __shared__ unsigned short lds_a[64 * 32];
    __shared__ unsigned short lds_b[512 * 32];
    __shared__ float yred[64];

    const int tid  = threadIdx.x;
    const int lane = tid & 63;
    const int w    = tid >> 6;
    const int q    = lane >> 4, r = lane & 15;
    const int b    = blockIdx.y;
    const int m0   = blockIdx.x * 64;

    if (tid < 64) yred[tid] = 0.f;

    f4 acc[4][8];
#pragma unroll
    for (int i = 0; i < 4; i++)
#pragma unroll
        for (int j = 0; j < 8; j++) { f4 zz = {0.f,0.f,0.f,0.f}; acc[i][j] = zz; }

    const int arow = tid >> 2;
    const int aseg = tid & 3;

    for (int kk = 0; kk < S_; kk += 32) {
        {
            u4* dst = (u4*)&lds_a[arow * 32 + aseg * 8];
            const int gl = m0 + arow;
            if (gl < L_) {
                const f4* src = (const f4*)(alpha + ((size_t)b * L_ + gl) * S_ + kk + aseg * 8);
                f4 v0 = src[0], v1 = src[1];
                u4 o;
                o[0] = pack2(v0[0], v0[1]); o[1] = pack2(v0[2], v0[3]);
                o[2] = pack2(v1[0], v1[1]); o[3] = pack2(v1[2], v1[3]);
                *dst = o;
            } else {
                u4 zz = {0,0,0,0}; *dst = zz;
            }
        }
#pragma unroll
        for (int jj = 0; jj < 8; jj++) {
            const int rr = arow + jj * 64;
            *(u4*)&lds_b[rr * 32 + aseg * 8] =
                *(const u4*)&zT[((size_t)(b * DA + rr)) * S_ + kk + aseg * 8];
        }
        __syncthreads();

        short8 af[4], bfr[8];
#pragma unroll
        for (int i = 0; i < 4; i++)
            af[i] = *(const short8*)&lds_a[(i * 16 + r) * 32 + q * 8];
#pragma unroll
        for (int j = 0; j < 8; j++)
            bfr[j] = *(const short8*)&lds_b[(w * 128 + j * 16 + r) * 32 + q * 8];
#pragma unroll
        for (int i = 0; i < 4; i++)
#pragma unroll
            for (int j = 0; j < 8; j++)
                acc[i][j] = __builtin_amdgcn_mfma_f32_16x16x32_bf16(af[i], bfr[j], acc[i][j], 0, 0, 0);
        __syncthreads();
    }

#pragma unroll
    for (int i = 0; i < 4; i++) {
#pragma unroll
        for (int e = 0; e < 4; e++) {
            const int rowl = i * 16 + q * 4 + e;
            const int gl = m0 + rowl;
            if (gl < L_) {
                float p = 0.f;
#pragma unroll
                for (int j = 0; j < 8; j++) {
                    const int col = w * 128 + j * 16 + r;
                    p += acc[i][j][e] * Vw[(size_t)gl * DA + col];
                }
                atomicAdd(&yred[rowl], p);
            }
        }
    }
    __syncthreads();
    if (tid < 64 && (m0 + tid) < L_)
        y[b * L_ + m0 + tid] = yred[tid] + Vb[m0 + tid];
}

// ---------------------------------------------------------------------------
extern "C" void kernel_launch(void* const* d_in, const int* in_sizes, int n_in,
                              void* d_out, int out_size, void* d_ws, size_t ws_size,
                              hipStream_t stream)
{
    const float* x  = (const float*)d_in[0];
    const float* Ww = (const float*)d_in[1];
    const float* Wb = (const float*)d_in[2];
    const float* Uw = (const float*)d_in[3];
    const float* Vw = (const float*)d_in[4];
    const float* Vb = (const float*)d_in[5];

    float* y     = (float*)d_out;
    float* alpha = y + (size_t)B_ * L_;   // outputs concatenated: y then alpha

    // Workspace layout (new path): [z bf16][U bf16][V bf16][T f32|bf16]
    unsigned short* z = (unsigned short*)d_ws;
    const size_t z_bytes  = (size_t)B_ * S_ * DA * 2;   // 16,384,000
    const size_t uv_bytes = (size_t)L_ * DA * 2;        //  9,135,104 (each)
    unsigned short* Ubf = (unsigned short*)((char*)d_ws + z_bytes);
    unsigned short* Vbf = (unsigned short*)((char*)d_ws + z_bytes + uv_bytes);
    char* Tp = (char*)d_ws + z_bytes + 2 * uv_bytes;    // 16B-aligned offset
    const size_t T_f32 = (size_t)B_ * L_ * S_ * 4;      // 570,944,000
    const size_t T_b16 = (size_t)B_ * L_ * S_ * 2;
    const size_t need_f32 = z_bytes + 2 * uv_bytes + T_f32;   // ~606 MB
    const size_t need_b16 = z_bytes + 2 * uv_bytes + T_b16;   // ~320 MB

    k_z<<<dim3(125, 4), dim3(256), 0, stream>>>(x, Ww, Wb, z);

    if (ws_size >= need_f32) {
        const int n8 = (L_ * DA) / 8;
        const int gc = (n8 + 255) / 256;
        k_cvt<<<dim3(gc), dim3(256), 0, stream>>>(Uw, Ubf, n8);
        k_cvt<<<dim3(gc), dim3(256), 0, stream>>>(Vw, Vbf, n8);
        k_uv<false><<<dim3(70, 32, B_), dim3(256), 0, stream>>>(Ubf, Vbf, z, alpha, (void*)Tp);
        k_fsy<false><<<dim3(B_ * L_), dim3(256), 0, stream>>>(alpha, (const void*)Tp, Vb, y);
    } else if (ws_size >= need_b16) {
        const int n8 = (L_ * DA) / 8;
        const int gc = (n8 + 255) / 256;
        k_cvt<<<dim3(gc), dim3(256), 0, stream>>>(Uw, Ubf, n8);
        k_cvt<<<dim3(gc), dim3(256), 0, stream>>>(Vw, Vbf, n8);
        k_uv<true><<<dim3(70, 32, B_), dim3(256), 0, stream>>>(Ubf, Vbf, z, alpha, (void*)Tp);
        k_fsy<true><<<dim3(B_ * L_), dim3(256), 0, stream>>>(alpha, (const void*)Tp, Vb, y);
    } else {
        // Fallback: previous verified path (needs only ~33 MB of ws)
        unsigned short* zT = z + (size_t)B_ * S_ * DA;
        k_scores<<<dim3(70, 32, B_), dim3(256), 0, stream>>>(Uw, z, alpha);
        k_softmax<<<dim3(B_ * L_), dim3(256), 0, stream>>>(alpha);
        k_transpose<<<dim3(125, 16, B_), dim3(256), 0, stream>>>(z, zT);
        k_mv<<<dim3(140, B_), dim3(256), 0, stream>>>(alpha, zT, Vw, Vb, y);
    }
}